// Round 6
// baseline (574.404 us; speedup 1.0000x reference)
//
#include <hip/hip_runtime.h>

#define N_NODES 100000
#define N_EDGES 3200000
#define D 256

#define NBKT 782           // row-buckets of 128 rows each (782*128 = 100096)
#define BCAP 4608          // entries per bucket; mean 4092, ~8 sigma margin
#define PART_BLOCKS 196    // 16384 edges per partition block (two-pass)
#define GEMM_BLOCKS 1564   // 6256 waves x 16 rows
#define CVT_BLOCKS 64      // 65536 W elems / (256*4)

using bf16x8 = __attribute__((ext_vector_type(8))) short;
using f32x4  = __attribute__((ext_vector_type(4))) float;
using i32x4  = __attribute__((ext_vector_type(4))) int;
using i32x2  = __attribute__((ext_vector_type(2))) int;

__device__ inline float bf2f(unsigned short b) {
    union { unsigned u; float f; } v; v.u = ((unsigned)b) << 16; return v.f;
}
__device__ inline unsigned short f2bf(float f) {
    union { float f; unsigned u; } v; v.f = f;
    unsigned u = v.u;
    u += 0x7FFFu + ((u >> 16) & 1u);   // round-to-nearest-even
    return (unsigned short)(u >> 16);
}

// ---- prep: [0,64) convert W fp32->bf16; rest init bucket_next ----
__global__ __launch_bounds__(256) void prep(const float* __restrict__ W,
                                            unsigned short* __restrict__ wb,
                                            int* __restrict__ bucket_next) {
    int bid = blockIdx.x;
    if (bid < CVT_BLOCKS) {
        int i = (bid * 256 + threadIdx.x) * 4;
        float4 f = *(const float4*)(W + i);
        ushort4 o;
        o.x = f2bf(f.x); o.y = f2bf(f.y); o.z = f2bf(f.z); o.w = f2bf(f.w);
        *(ushort4*)(wb + i) = o;
    } else {
        int t = (bid - CVT_BLOCKS) * 256 + threadIdx.x;
        if (t < NBKT) bucket_next[t] = t * BCAP;
    }
}

// ---- GEMM: one wave = 16(M) x 256(N) strip of support = X @ W^T ----
// Key fix vs prior rounds: ALL 16 b-fragments are loaded into registers
// BEFORE the MFMA chain (a-loads issued first). Compiler then emits
// pipelined vmcnt(15..0) waits instead of 16 serialized full-latency
// load->waitcnt(0)->mfma round-trips per k0 step.
__global__ __launch_bounds__(256) void gemm(
    const float* __restrict__ x,            // [N_NODES, 256] fp32
    const unsigned short* __restrict__ wb,  // [256, 256] bf16
    unsigned short* __restrict__ sb)        // [N_NODES, 256] bf16 out
{
    int wave = blockIdx.x * 4 + (int)(threadIdx.x >> 6);
    int m0 = wave << 4;
    if (m0 >= N_NODES) return;
    int lane = threadIdx.x & 63;
    int quad = lane >> 4;
    int r16  = lane & 15;

    const f32x4* arow = (const f32x4*)(x + (size_t)(m0 + r16) * D + quad * 8);
    const unsigned short* bbase = wb + (size_t)r16 * D + quad * 8;

    f32x4 acc[16];
#pragma unroll
    for (int t = 0; t < 16; ++t) acc[t] = (f32x4){0.f, 0.f, 0.f, 0.f};

    for (int k0 = 0; k0 < D; k0 += 32) {
        // a-loads first (x is L3-cacheable now: re-read every iteration)
        f32x4 fa0 = *(arow + (k0 >> 2));
        f32x4 fa1 = *(arow + (k0 >> 2) + 1);
        // hoist all 16 b-fragments -> 16 outstanding loads, pipelined waits
        bf16x8 bf[16];
#pragma unroll
        for (int t = 0; t < 16; ++t)
            bf[t] = *(const bf16x8*)(bbase + (size_t)t * 16 * D + k0);
        bf16x8 a;
        a[0] = (short)f2bf(fa0[0]); a[1] = (short)f2bf(fa0[1]);
        a[2] = (short)f2bf(fa0[2]); a[3] = (short)f2bf(fa0[3]);
        a[4] = (short)f2bf(fa1[0]); a[5] = (short)f2bf(fa1[1]);
        a[6] = (short)f2bf(fa1[2]); a[7] = (short)f2bf(fa1[3]);
#pragma unroll
        for (int t = 0; t < 16; ++t)
            acc[t] = __builtin_amdgcn_mfma_f32_16x16x32_bf16(bf[t], a, acc[t], 0, 0, 0);
    }

#pragma unroll
    for (int t = 0; t < 16; ++t) {
        ushort4 o;
        o.x = f2bf(acc[t][0]); o.y = f2bf(acc[t][1]);
        o.z = f2bf(acc[t][2]); o.w = f2bf(acc[t][3]);
        *(ushort4*)(sb + (size_t)(m0 + r16) * D + t * 16 + quad * 4) = o;
    }
}

// ---- partition: 196 blocks x 16384 edges, two-pass ----
// Pass1: LDS histogram (non-returning LDS atomics). Reserve: 782 global
// atomics/block (153K total vs 611K before, and larger per-(block,bucket)
// runs ~21 edges -> near-coalesced bkt writes). Pass2: re-read edges,
// returning LDS atomic gives the global destination cursor directly.
__global__ __launch_bounds__(1024) void part(
    const i32x4* __restrict__ erow4,
    const i32x4* __restrict__ ecol4,
    const f32x4* __restrict__ eval4,
    int* __restrict__ bucket_next,          // [NBKT], pre-set to b*BCAP
    i32x2* __restrict__ bkt)                // [NBKT*BCAP]
{
    __shared__ int h_cnt[NBKT];             // count, then global cursor
    int p = blockIdx.x, tid = threadIdx.x;
    for (int i = tid; i < NBKT; i += 1024) h_cnt[i] = 0;
    __syncthreads();
    int q0 = p * 4096;                      // i32x4 groups (16384 edges)
#pragma unroll
    for (int j = 0; j < 4; ++j) {
        int q = q0 + j * 1024 + tid;
        if (q < N_EDGES / 4) {
            i32x4 r4 = erow4[q];
#pragma unroll
            for (int k = 0; k < 4; ++k)
                atomicAdd(&h_cnt[r4[k] >> 7], 1);   // LDS, non-returning
        }
    }
    __syncthreads();
    for (int i = tid; i < NBKT; i += 1024)
        h_cnt[i] = atomicAdd(&bucket_next[i], h_cnt[i]);  // -> global cursor
    __syncthreads();
#pragma unroll
    for (int j = 0; j < 4; ++j) {
        int q = q0 + j * 1024 + tid;
        if (q < N_EDGES / 4) {
            i32x4 r4 = erow4[q];
            i32x4 c4 = ecol4[q];
            f32x4 v4 = eval4[q];
#pragma unroll
            for (int k = 0; k < 4; ++k) {
                int row = r4[k];
                int b   = row >> 7;
                int dst = atomicAdd(&h_cnt[b], 1);  // LDS, returning
                if (dst < (b + 1) * BCAP) {         // ~8-sigma safety clamp
                    i32x2 o; o[0] = c4[k] | ((row & 127) << 24);
                    o[1] = __float_as_int(v4[k]);
                    bkt[dst] = o;
                }
            }
        }
    }
}

// ---- fused group + gather: one 512-thread block per 128-row bucket ----
__global__ __launch_bounds__(512) void csr_spmm(
    const int* __restrict__ bucket_next,
    const i32x2* __restrict__ bkt,
    const unsigned short* __restrict__ sb, float* __restrict__ out)
{
    __shared__ int2 lds_e[BCAP];        // 36,864 B
    __shared__ int cnt[128], scn[128], cur[128];
    int b = blockIdx.x, tid = threadIdx.x;
    int base = b * BCAP;
    int ne = bucket_next[b] - base; if (ne > BCAP) ne = BCAP;

    if (tid < 128) cnt[tid] = 0;
    __syncthreads();
    for (int idx = tid; idx < ne; idx += 512) {
        i32x2 e = bkt[base + idx];
        atomicAdd(&cnt[((unsigned)e[0]) >> 24], 1);
    }
    __syncthreads();
    if (tid < 128) scn[tid] = cnt[tid];
    __syncthreads();
    for (int off = 1; off < 128; off <<= 1) {      // Hillis-Steele over 128
        int v = 0;
        if (tid < 128 && tid >= off) v = scn[tid - off];
        __syncthreads();
        if (tid < 128) scn[tid] += v;
        __syncthreads();
    }
    if (tid < 128) { int ex = scn[tid] - cnt[tid]; scn[tid] = ex; cur[tid] = ex; }
    __syncthreads();
    for (int idx = tid; idx < ne; idx += 512) {    // bucket region is L2-hot
        i32x2 e = bkt[base + idx];
        int rl  = ((unsigned)e[0]) >> 24;
        int pos = atomicAdd(&cur[rl], 1);
        lds_e[pos] = make_int2(e[0] & 0x00FFFFFF, e[1]);
    }
    __syncthreads();

    int wid = tid >> 6, lane = tid & 63, hi = lane >> 5;
    const unsigned short* basep = sb + (size_t)(lane & 31) * 8;  // 8 ch/lane

#define PAIR(AA, BB, EE) do {                                        \
        int2 pa = lds_e[EE];                                         \
        int2 pb = lds_e[(EE) + 1];                                   \
        int   col = hi ? pb.x : pa.x;                                \
        float v   = __int_as_float(hi ? pb.y : pa.y);                \
        bf16x8 s = *(const bf16x8*)(basep + ((size_t)col << 8));     \
        AA[0] += v * bf2f((unsigned short)s[0]);                     \
        AA[1] += v * bf2f((unsigned short)s[1]);                     \
        AA[2] += v * bf2f((unsigned short)s[2]);                     \
        AA[3] += v * bf2f((unsigned short)s[3]);                     \
        BB[0] += v * bf2f((unsigned short)s[4]);                     \
        BB[1] += v * bf2f((unsigned short)s[5]);                     \
        BB[2] += v * bf2f((unsigned short)s[6]);                     \
        BB[3] += v * bf2f((unsigned short)s[7]);                     \
    } while (0)

    for (int r = 0; r < 16; ++r) {
        int rl  = wid * 16 + r;
        int row = (b << 7) + rl;
        if (row >= N_NODES) break;
        int e   = scn[rl];
        int end = cur[rl];

        f32x4 a0 = {0.f,0.f,0.f,0.f}, b0 = {0.f,0.f,0.f,0.f};
        f32x4 a1 = {0.f,0.f,0.f,0.f}, b1 = {0.f,0.f,0.f,0.f};
        f32x4 a2 = {0.f,0.f,0.f,0.f}, b2 = {0.f,0.f,0.f,0.f};
        f32x4 a3 = {0.f,0.f,0.f,0.f}, b3 = {0.f,0.f,0.f,0.f};

        for (; e + 8 <= end; e += 8) {
            PAIR(a0, b0, e);
            PAIR(a1, b1, e + 2);
            PAIR(a2, b2, e + 4);
            PAIR(a3, b3, e + 6);
        }
        for (; e + 2 <= end; e += 2) PAIR(a0, b0, e);
        if (e < end) {                               // odd tail: hi half idle
            int2 pa = lds_e[e];
            int   col = pa.x;
            float v   = hi ? 0.f : __int_as_float(pa.y);
            bf16x8 s = *(const bf16x8*)(basep + ((size_t)col << 8));
            a0[0] += v * bf2f((unsigned short)s[0]);
            a0[1] += v * bf2f((unsigned short)s[1]);
            a0[2] += v * bf2f((unsigned short)s[2]);
            a0[3] += v * bf2f((unsigned short)s[3]);
            b0[0] += v * bf2f((unsigned short)s[4]);
            b0[1] += v * bf2f((unsigned short)s[5]);
            b0[2] += v * bf2f((unsigned short)s[6]);
            b0[3] += v * bf2f((unsigned short)s[7]);
        }

        f32x4 A = (a0 + a1) + (a2 + a3);
        f32x4 B = (b0 + b1) + (b2 + b3);
#pragma unroll
        for (int j = 0; j < 4; ++j) {
            A[j] += __shfl_xor(A[j], 32);
            B[j] += __shfl_xor(B[j], 32);
        }
        if (lane < 32) {
            float* o = out + (size_t)row * D + lane * 8;
            __builtin_nontemporal_store(A, (f32x4*)o);
            __builtin_nontemporal_store(B, (f32x4*)(o + 4));
        }
    }
#undef PAIR
}

extern "C" void kernel_launch(void* const* d_in, const int* in_sizes, int n_in,
                              void* d_out, int out_size, void* d_ws, size_t ws_size,
                              hipStream_t stream) {
    const float* x    = (const float*)d_in[0];
    const float* W    = (const float*)d_in[1];
    const int*   erow = (const int*)d_in[2];
    const int*   ecol = (const int*)d_in[3];
    const float* eval = (const float*)d_in[4];
    float* out = (float*)d_out;

    // ---- workspace layout (bytes) ----
    char* ws = (char*)d_ws;
    unsigned short* wb    = (unsigned short*)(ws + 0);          // 131,072
    unsigned short* sb    = (unsigned short*)(ws + 131072);     // 51,200,000
    int*            bnext = (int*)(ws + 51331072);              // 3,128 (4KB pad)
    i32x2*          bkt   = (i32x2*)(ws + 51335168);            // 28,827,648
    // total 80,162,816 bytes (~80 MB)

    prep<<<CVT_BLOCKS + 4, 256, 0, stream>>>(W, wb, bnext);

    gemm<<<GEMM_BLOCKS, 256, 0, stream>>>(x, wb, sb);

    part<<<PART_BLOCKS, 1024, 0, stream>>>(
        (const i32x4*)erow, (const i32x4*)ecol, (const f32x4*)eval, bnext, bkt);

    csr_spmm<<<NBKT, 512, 0, stream>>>(bnext, bkt, sb, out);
}